// Round 1
// baseline (71.559 us; speedup 1.0000x reference)
//
#include <hip/hip_runtime.h>

typedef __bf16 bf16_t;
typedef bf16_t bf16x8 __attribute__((ext_vector_type(8)));
typedef float f32x4 __attribute__((ext_vector_type(4)));

#define Bsz 4096   // batch rows (M)
#define Csz 4096   // centers (N)
#define Dsz 1024   // data dim (K)
#define BM 128
#define BN 128
#define BK 64
#define NKT (Dsz/BK)   // 16 K-tiles
#define NTILES_N (Csz/BN)  // 32

// RNE f32 -> bf16 bits
__device__ inline unsigned short f2bf(float f){
  unsigned u = __float_as_uint(f);
  u += 0x7FFFu + ((u >> 16) & 1u);
  return (unsigned short)(u >> 16);
}

// ---------------- prep: x2/c2 (f32 exact) + bf16 conversion ----------------
__global__ __launch_bounds__(256) void prep_kernel(
    const float* __restrict__ x, const float* __restrict__ cen,
    unsigned short* __restrict__ xb, unsigned short* __restrict__ cb,
    float* __restrict__ x2, float* __restrict__ c2)
{
  int w = blockIdx.x * 4 + (threadIdx.x >> 6);   // global wave id, one row each
  int lane = threadIdx.x & 63;
  const float* src; unsigned short* dst; float* sq; int row;
  if (w < Bsz) { row = w;       src = x;   dst = xb; sq = x2; }
  else         { row = w - Bsz; src = cen; dst = cb; sq = c2; }

  const float4* s4 = (const float4*)(src + (size_t)row * Dsz);
  unsigned short* d = dst + (size_t)row * Dsz;
  float ss = 0.f;
  #pragma unroll
  for (int t = 0; t < 4; ++t){
    float4 v = s4[t * 64 + lane];
    ss += v.x*v.x + v.y*v.y + v.z*v.z + v.w*v.w;
    ushort4 u; u.x = f2bf(v.x); u.y = f2bf(v.y); u.z = f2bf(v.z); u.w = f2bf(v.w);
    *(ushort4*)(d + (size_t)(t * 64 + lane) * 4) = u;
  }
  #pragma unroll
  for (int off = 32; off >= 1; off >>= 1) ss += __shfl_xor(ss, off, 64);
  if (lane == 0) sq[row] = ss;
}

// ---------------- main fused GEMM + RBF epilogue ----------------
// Block: 256 thr = 4 waves. Tile 128x128, BK=64.
// Wave w owns rows [w*32, w*32+32) x all 128 cols: 2x8 frags of 16x16x32 MFMA.
// LDS tiles XOR-swizzled in 16B chunks: LDS[r][c] = G[r][c ^ (r&7)]
// (linear global_load_lds dest + pre-swizzled global source + swizzled ds_read).
__global__ __launch_bounds__(256) void rbf_gemm_kernel(
    const unsigned short* __restrict__ xb, const unsigned short* __restrict__ cb,
    const float* __restrict__ x2, const float* __restrict__ c2,
    const float* __restrict__ beta, const float* __restrict__ W,
    float* __restrict__ partials)
{
  __shared__ __align__(16) unsigned short As[BM * BK];
  __shared__ __align__(16) unsigned short Bs[BN * BK];

  const int tid  = threadIdx.x;
  const int w    = tid >> 6;
  const int lane = tid & 63;
  const int l15  = lane & 15;
  const int lhi  = lane >> 4;
  const int brow = blockIdx.x * BM;
  const int bcol = blockIdx.y * BN;

  f32x4 acc[2][8];
  #pragma unroll
  for (int mi = 0; mi < 2; ++mi)
    #pragma unroll
    for (int ni = 0; ni < 8; ++ni)
      acc[mi][ni] = (f32x4){0.f, 0.f, 0.f, 0.f};

  // staging geometry: each global_load_lds covers 8 rows x 128B (1KB)
  const int srow   = lane >> 3;            // row within 8-row group
  const int schunk = (lane & 7) ^ srow;    // pre-swizzled source 16B-chunk
  const unsigned short* gA = xb + (size_t)brow * Dsz;
  const unsigned short* gB = cb + (size_t)bcol * Dsz;

  for (int kt = 0; kt < NKT; ++kt){
    #pragma unroll
    for (int t = 0; t < 4; ++t){
      const int r0 = w * 32 + t * 8;
      const unsigned short* ga = gA + (size_t)(r0 + srow) * Dsz + kt * BK + schunk * 8;
      __builtin_amdgcn_global_load_lds(
          (const __attribute__((address_space(1))) unsigned int*)ga,
          (__attribute__((address_space(3))) unsigned int*)&As[r0 * BK], 16, 0, 0);
      const unsigned short* gb = gB + (size_t)(r0 + srow) * Dsz + kt * BK + schunk * 8;
      __builtin_amdgcn_global_load_lds(
          (const __attribute__((address_space(1))) unsigned int*)gb,
          (__attribute__((address_space(3))) unsigned int*)&Bs[r0 * BK], 16, 0, 0);
    }
    __syncthreads();   // compiler drains vmcnt before barrier -> LDS tiles ready

    #pragma unroll
    for (int kk = 0; kk < 2; ++kk){
      bf16x8 av[2], bv[8];
      const int chunk = (kk * 4 + lhi) ^ (l15 & 7);
      #pragma unroll
      for (int mi = 0; mi < 2; ++mi){
        int ra = w * 32 + mi * 16 + l15;
        av[mi] = *reinterpret_cast<const bf16x8*>(&As[ra * BK + chunk * 8]);
      }
      #pragma unroll
      for (int ni = 0; ni < 8; ++ni){
        int rb = ni * 16 + l15;
        bv[ni] = *reinterpret_cast<const bf16x8*>(&Bs[rb * BK + chunk * 8]);
      }
      #pragma unroll
      for (int mi = 0; mi < 2; ++mi)
        #pragma unroll
        for (int ni = 0; ni < 8; ++ni)
          acc[mi][ni] = __builtin_amdgcn_mfma_f32_16x16x32_bf16(av[mi], bv[ni], acc[mi][ni], 0, 0, 0);
    }
    __syncthreads();   // protect LDS before next stage overwrites
  }

  // ---- fused epilogue: d2 -> dist -> exp -> *W, then column-sum ----
  float x2r[2][4];
  #pragma unroll
  for (int mi = 0; mi < 2; ++mi)
    #pragma unroll
    for (int j = 0; j < 4; ++j)
      x2r[mi][j] = x2[brow + w * 32 + mi * 16 + lhi * 4 + j];

  float rsum[2][4] = {{0.f,0.f,0.f,0.f},{0.f,0.f,0.f,0.f}};
  #pragma unroll
  for (int ni = 0; ni < 8; ++ni){
    int col = bcol + ni * 16 + l15;
    float c2v = c2[col], bt = beta[col], wv = W[col];
    #pragma unroll
    for (int mi = 0; mi < 2; ++mi)
      #pragma unroll
      for (int j = 0; j < 4; ++j){
        float s    = acc[mi][ni][j];
        float d2   = x2r[mi][j] + c2v - 2.0f * s;
        float dist = sqrtf(fmaxf(d2, 0.0f));
        rsum[mi][j] += wv * expf(-bt * dist);   // exp(<=0) can't be inf
      }
  }

  // reduce across the 16 lanes holding different cols of a frag row
  #pragma unroll
  for (int mi = 0; mi < 2; ++mi)
    #pragma unroll
    for (int j = 0; j < 4; ++j){
      float v = rsum[mi][j];
      v += __shfl_xor(v, 1, 16);
      v += __shfl_xor(v, 2, 16);
      v += __shfl_xor(v, 4, 16);
      v += __shfl_xor(v, 8, 16);
      if (l15 == 0){
        int row = brow + w * 32 + mi * 16 + lhi * 4 + j;
        partials[(size_t)blockIdx.y * Bsz + row] = v;
      }
    }
}

// ---------------- final reduction over N-tiles ----------------
__global__ __launch_bounds__(256) void reduce_kernel(
    const float* __restrict__ partials, const float* __restrict__ bias,
    float* __restrict__ out)
{
  int b = blockIdx.x * 256 + threadIdx.x;
  float s = bias[0];
  #pragma unroll
  for (int t = 0; t < NTILES_N; ++t) s += partials[(size_t)t * Bsz + b];
  out[b] = s;
}

// ---------------- naive f32 fallback (only if ws too small) ----------------
__global__ __launch_bounds__(256) void rbf_naive_kernel(
    const float* __restrict__ x, const float* __restrict__ cen,
    const float* __restrict__ beta, const float* __restrict__ W,
    const float* __restrict__ bias, float* __restrict__ out)
{
  __shared__ float4 xs4[Dsz / 4];
  __shared__ float red[256];
  int b = blockIdx.x;
  for (int i = threadIdx.x; i < Dsz / 4; i += 256)
    xs4[i] = ((const float4*)(x + (size_t)b * Dsz))[i];
  __syncthreads();
  float acc = 0.f;
  for (int j = threadIdx.x; j < Csz; j += 256){
    const float4* c4 = (const float4*)(cen + (size_t)j * Dsz);
    float d2 = 0.f;
    for (int k = 0; k < Dsz / 4; ++k){
      float4 cv = c4[k], xv = xs4[k];
      float a0 = xv.x - cv.x, a1 = xv.y - cv.y, a2 = xv.z - cv.z, a3 = xv.w - cv.w;
      d2 += a0*a0 + a1*a1 + a2*a2 + a3*a3;
    }
    acc += W[j] * expf(-beta[j] * sqrtf(fmaxf(d2, 0.f)));
  }
  red[threadIdx.x] = acc;
  __syncthreads();
  for (int s = 128; s >= 1; s >>= 1){
    if (threadIdx.x < s) red[threadIdx.x] += red[threadIdx.x + s];
    __syncthreads();
  }
  if (threadIdx.x == 0) out[b] = red[0] + bias[0];
}

extern "C" void kernel_launch(void* const* d_in, const int* in_sizes, int n_in,
                              void* d_out, int out_size, void* d_ws, size_t ws_size,
                              hipStream_t stream)
{
  const float* x    = (const float*)d_in[0];
  const float* cen  = (const float*)d_in[1];
  const float* beta = (const float*)d_in[2];
  const float* W    = (const float*)d_in[3];
  const float* bias = (const float*)d_in[4];
  float* out = (float*)d_out;

  const size_t off_xb = 0;
  const size_t off_cb = off_xb + (size_t)Bsz * Dsz * sizeof(unsigned short);
  const size_t off_x2 = off_cb + (size_t)Csz * Dsz * sizeof(unsigned short);
  const size_t off_c2 = off_x2 + (size_t)Bsz * sizeof(float);
  const size_t off_p  = off_c2 + (size_t)Csz * sizeof(float);
  const size_t need   = off_p  + (size_t)NTILES_N * Bsz * sizeof(float);

  if (ws_size < need){
    rbf_naive_kernel<<<Bsz, 256, 0, stream>>>(x, cen, beta, W, bias, out);
    return;
  }

  char* ws = (char*)d_ws;
  unsigned short* xb = (unsigned short*)(ws + off_xb);
  unsigned short* cb = (unsigned short*)(ws + off_cb);
  float* x2 = (float*)(ws + off_x2);
  float* c2 = (float*)(ws + off_c2);
  float* pp = (float*)(ws + off_p);

  prep_kernel<<<(Bsz + Csz) / 4, 256, 0, stream>>>(x, cen, xb, cb, x2, c2);
  dim3 grid(Bsz / BM, Csz / BN);
  rbf_gemm_kernel<<<grid, 256, 0, stream>>>(xb, cb, x2, c2, beta, W, pp);
  reduce_kernel<<<Bsz / 256, 256, 0, stream>>>(pp, bias, out);
}